// Round 3
// baseline (159.955 us; speedup 1.0000x reference)
//
#include <hip/hip_runtime.h>

#define NCLS 19
#define CM_BINS (NCLS * NCLS)   // 361; ws[361] = done-counter
#define EPS 1e-5f
#define HW 262144               // 512*512
#define BLOCK 256
#define GRID 2048

typedef float f32x4 __attribute__((ext_vector_type(4)));
typedef int   i32x4 __attribute__((ext_vector_type(4)));

#define NTLOAD(ptr) __builtin_nontemporal_load(reinterpret_cast<const f32x4*>(ptr))

#define CMP1(c, v)                                          \
    do {                                                    \
        if ((v).x > best.x) { best.x = (v).x; bcx = (c); }  \
        if ((v).y > best.y) { best.y = (v).y; bcy = (c); }  \
        if ((v).z > best.z) { best.z = (v).z; bcz = (c); }  \
        if ((v).w > best.w) { best.w = (v).w; bcw = (c); }  \
    } while (0)

__global__ void __launch_bounds__(BLOCK, 6)
dice_cm_kernel(const float* __restrict__ y_pred,
               const int* __restrict__ y,
               unsigned int* __restrict__ ws,
               float* __restrict__ out,
               int n_vec) {
    __shared__ unsigned int s_cm[CM_BINS];
    __shared__ unsigned int s_last;
    const int tid = threadIdx.x;
    for (int i = tid; i < CM_BINS; i += BLOCK) s_cm[i] = 0u;
    __syncthreads();

    for (int pv = blockIdx.x * BLOCK + tid; pv < n_vec; pv += GRID * BLOCK) {
        const int b   = pv >> 16;        // pv / (HW/4)
        const int hw4 = pv & 65535;      // pv % (HW/4)
        const float* p = y_pred + (size_t)b * ((size_t)NCLS * HW) + (size_t)hw4 * 4;

        const i32x4 lab = __builtin_nontemporal_load(
            reinterpret_cast<const i32x4*>(y) + pv);

        // argmax over 19 planes, batches of 4 to cap live VGPRs (occupancy)
        f32x4 best = NTLOAD(p);
        int bcx = 0, bcy = 0, bcz = 0, bcw = 0;
        {
            f32x4 a = NTLOAD(p + 1 * (size_t)HW), b2 = NTLOAD(p + 2 * (size_t)HW),
                  c = NTLOAD(p + 3 * (size_t)HW), d = NTLOAD(p + 4 * (size_t)HW);
            CMP1(1, a); CMP1(2, b2); CMP1(3, c); CMP1(4, d);
        }
        {
            f32x4 a = NTLOAD(p + 5 * (size_t)HW), b2 = NTLOAD(p + 6 * (size_t)HW),
                  c = NTLOAD(p + 7 * (size_t)HW), d = NTLOAD(p + 8 * (size_t)HW);
            CMP1(5, a); CMP1(6, b2); CMP1(7, c); CMP1(8, d);
        }
        {
            f32x4 a = NTLOAD(p + 9 * (size_t)HW), b2 = NTLOAD(p + 10 * (size_t)HW),
                  c = NTLOAD(p + 11 * (size_t)HW), d = NTLOAD(p + 12 * (size_t)HW);
            CMP1(9, a); CMP1(10, b2); CMP1(11, c); CMP1(12, d);
        }
        {
            f32x4 a = NTLOAD(p + 13 * (size_t)HW), b2 = NTLOAD(p + 14 * (size_t)HW),
                  c = NTLOAD(p + 15 * (size_t)HW), d = NTLOAD(p + 16 * (size_t)HW);
            CMP1(13, a); CMP1(14, b2); CMP1(15, c); CMP1(16, d);
        }
        {
            f32x4 a = NTLOAD(p + 17 * (size_t)HW), b2 = NTLOAD(p + 18 * (size_t)HW);
            CMP1(17, a); CMP1(18, b2);
        }

        atomicAdd(&s_cm[lab.x * NCLS + bcx], 1u);
        atomicAdd(&s_cm[lab.y * NCLS + bcy], 1u);
        atomicAdd(&s_cm[lab.z * NCLS + bcz], 1u);
        atomicAdd(&s_cm[lab.w * NCLS + bcw], 1u);
    }

    __syncthreads();
    for (int i = tid; i < CM_BINS; i += BLOCK) {
        const unsigned int v = s_cm[i];
        if (v) atomicAdd(&ws[i], v);
    }
    __syncthreads();   // barrier drains each thread's outstanding atomics

    if (tid == 0) {
        __threadfence();
        s_last = (atomicAdd(&ws[CM_BINS], 1u) == GRID - 1) ? 1u : 0u;
    }
    __syncthreads();

    if (s_last) {
        // last block: all prior flushes are at the coherence point; read via
        // atomic fetch-add(0) to get L2-current values (cross-XCD safe)
        for (int i = tid; i < CM_BINS; i += BLOCK)
            s_cm[i] = atomicAdd(&ws[i], 0u);
        __syncthreads();
        if (tid < 64) {
            float d = 0.0f;
            if (tid < NCLS) {
                float cy = 0.0f, cp = 0.0f;
                #pragma unroll
                for (int j = 0; j < NCLS; ++j) {
                    cy += (float)s_cm[tid * NCLS + j];
                    cp += (float)s_cm[j * NCLS + tid];
                }
                const float inter = (float)s_cm[tid * NCLS + tid];
                d = (2.0f * inter + EPS) / (cy + cp - inter + EPS);
            }
            #pragma unroll
            for (int off = 32; off > 0; off >>= 1) d += __shfl_down(d, off);
            if (tid == 0) out[0] = 1.0f - d * (1.0f / (float)NCLS);
        }
    }
}

extern "C" void kernel_launch(void* const* d_in, const int* in_sizes, int n_in,
                              void* d_out, int out_size, void* d_ws, size_t ws_size,
                              hipStream_t stream) {
    const float* y_pred = (const float*)d_in[0];
    const int*   y      = (const int*)d_in[1];
    float*       out    = (float*)d_out;
    unsigned int* ws    = (unsigned int*)d_ws;

    // zero cm[361] + done-counter[1]
    hipMemsetAsync(ws, 0, (CM_BINS + 1) * sizeof(unsigned int), stream);

    const int n_pix = in_sizes[1];     // 16*512*512
    const int n_vec = n_pix / 4;       // 1,048,576 -> exactly 2 iters/thread

    dice_cm_kernel<<<GRID, BLOCK, 0, stream>>>(y_pred, y, ws, out, n_vec);
}